// Round 7
// baseline (337.100 us; speedup 1.0000x reference)
//
#include <hip/hip_runtime.h>
#include <cstdint>
#include <cstddef>

// Problem constants
#define BB 2
#define SS 2048
#define DD 1024
#define HH 16
#define HDIM 64
// Attention scale 1/sqrt(64)=0.125 and the exp->exp2 fold log2(e) are
// pre-multiplied into q at the gemm_qkv epilogue: 0.125*1.4426950 = 0.18033688.

typedef short bf16x8 __attribute__((ext_vector_type(8)));
typedef short bf16x4 __attribute__((ext_vector_type(4)));
typedef float f32x4 __attribute__((ext_vector_type(4)));

union U4S8 { uint4 u; bf16x8 s; };
union U2S4 { uint2 u; bf16x4 s; unsigned short h[4]; };

// 16x16x16 bf16 MFMA (K=16). __has_builtin(amdgcn) is FALSE in the host pass
// of HIP's dual compile — guard with __HIP_DEVICE_COMPILE__, dummy for host.
#if defined(__HIP_DEVICE_COMPILE__)
# if __has_builtin(__builtin_amdgcn_mfma_f32_16x16x16bf16_1k)
#  define MFMA_PV(a, b, c) __builtin_amdgcn_mfma_f32_16x16x16bf16_1k((a), (b), (c), 0, 0, 0)
# else
#  define MFMA_PV(a, b, c) __builtin_amdgcn_mfma_f32_16x16x16_bf16((a), (b), (c), 0, 0, 0)
# endif
#else
# define MFMA_PV(a, b, c) (c)
#endif

__device__ __forceinline__ unsigned short f2bf(float f) {
    union { float f; unsigned int u; } c; c.f = f;
    unsigned int u = c.u;
    unsigned int r = (u + 0x7FFFu + ((u >> 16) & 1u)) >> 16;  // RTNE
    return (unsigned short)r;
}
// cheap round (ties-away): 2 VALU ops. For P in [0,1] error ~2^-10 relative.
__device__ __forceinline__ unsigned short f2bf_fast(float f) {
    union { float f; unsigned int u; } c; c.f = f;
    return (unsigned short)((c.u + 0x8000u) >> 16);
}

// async global->LDS, 16B per lane. LDS dest must be wave-uniform base + lane*16.
__device__ __forceinline__ void async_cp16(const void* g, void* l) {
    __builtin_amdgcn_global_load_lds(
        (const __attribute__((address_space(1))) void*)g,
        (__attribute__((address_space(3))) void*)l, 16, 0, 0);
}

// ---------------------------------------------------------------- fp32 -> bf16
// One kernel for all three inputs (x:524288, w_qkv:393216, w_out:131072 uint4s).
__global__ __launch_bounds__(256) void cvt_all(
    const float* __restrict__ x, const float* __restrict__ wq,
    const float* __restrict__ wo,
    unsigned short* __restrict__ xb, unsigned short* __restrict__ wqb,
    unsigned short* __restrict__ wob) {
    int i = blockIdx.x * 256 + threadIdx.x;
    const float* in; unsigned short* out; int j;
    if (i < 524288)       { in = x;  out = xb;  j = i; }
    else if (i < 917504)  { in = wq; out = wqb; j = i - 524288; }
    else                  { in = wo; out = wob; j = i - 917504; }
    float4 a = ((const float4*)in)[2 * j];
    float4 b = ((const float4*)in)[2 * j + 1];
    union { uint4 u; unsigned short h[8]; } o;
    o.h[0] = f2bf(a.x); o.h[1] = f2bf(a.y); o.h[2] = f2bf(a.z); o.h[3] = f2bf(a.w);
    o.h[4] = f2bf(b.x); o.h[5] = f2bf(b.y); o.h[6] = f2bf(b.z); o.h[7] = f2bf(b.w);
    ((uint4*)out)[j] = o.u;
}

// ---------------------------------------------------------------- QKV GEMM
// C[m,e] = sum_d x[m,d] * w_qkv[e,d]  (NT). M=4096, N=3072, K=1024.
// 128x128 tile, BK=32, global_load_lds width-16 staging.
// v epilogue transposes through LDS -> coalesced [B,H,HD,S] uint4 stores.
__global__ __launch_bounds__(256) void gemm_qkv(
    const unsigned short* __restrict__ A,   // x_bf   [4096][1024]
    const unsigned short* __restrict__ Bw,  // wqkv_bf[3072][1024]
    unsigned short* __restrict__ qb, unsigned short* __restrict__ kb,
    unsigned short* __restrict__ vb) {
    const int K = 1024;
    __shared__ unsigned short As[128 * 32];
    __shared__ unsigned short Bs[128 * 32];
    __shared__ unsigned short Tr[4][64 * 72];  // per-wave transpose buffer (v epilogue)
    int tid = threadIdx.x;
    int lane = tid & 63, wave = tid >> 6;
    int wm = (wave & 1) * 64, wn = (wave >> 1) * 64;
    int m0 = blockIdx.y * 128, n0 = blockIdx.x * 128;
    int lm = lane & 15, lq = lane >> 4;

    f32x4 acc[4][4] = {};

    int srow = tid >> 2, schunk = tid & 3;
    const unsigned short* gA = A  + (size_t)(m0 + srow) * K + schunk * 8;
    const unsigned short* gB = Bw + (size_t)(n0 + srow) * K + schunk * 8;
    unsigned short* lA = As + srow * 32 + schunk * 8;
    unsigned short* lB = Bs + srow * 32 + schunk * 8;

    for (int k0 = 0; k0 < K; k0 += 32) {
        async_cp16(gA + k0,           lA);
        async_cp16(gA + 64 * K + k0,  lA + 64 * 32);
        async_cp16(gB + k0,           lB);
        async_cp16(gB + 64 * K + k0,  lB + 64 * 32);
        __syncthreads();
        U4S8 af[4], bfx[4];
        #pragma unroll
        for (int i = 0; i < 4; i++) {
            af[i].u  = *(const uint4*)(As + (wm + i * 16 + lm) * 32 + lq * 8);
            bfx[i].u = *(const uint4*)(Bs + (wn + i * 16 + lm) * 32 + lq * 8);
        }
        #pragma unroll
        for (int mi = 0; mi < 4; mi++)
            #pragma unroll
            for (int ni = 0; ni < 4; ni++)
                acc[mi][ni] = __builtin_amdgcn_mfma_f32_16x16x32_bf16(
                    af[mi].s, bfx[ni].s, acc[mi][ni], 0, 0, 0);
        __syncthreads();
    }

    // Epilogue. C/D layout: col=lane&15, row=(lane>>4)*4+reg.
    if (n0 < 1024) {
        // ---- v: transpose wave's 64x64 subtile via LDS, store [B,H,HD,S] coalesced
        int h = (n0 + wn) >> 6;
        #pragma unroll
        for (int mi = 0; mi < 4; mi++)
            #pragma unroll
            for (int ni = 0; ni < 4; ni++)
                #pragma unroll
                for (int r = 0; r < 4; r++)
                    Tr[wave][(ni * 16 + lm) * 72 + mi * 16 + lq * 4 + r] =
                        f2bf(acc[mi][ni][r]);
        __builtin_amdgcn_wave_barrier();
        int b = m0 >> 11;
        int s_base = (m0 + wm) & 2047;
        unsigned short* vdst = vb + ((size_t)(b * HH + h) * HDIM) * SS + s_base;
        #pragma unroll
        for (int it = 0; it < 8; it++) {
            int hd = it * 8 + (lane >> 3);
            int so = (lane & 7) * 8;
            uint4 val = *(const uint4*)&Tr[wave][hd * 72 + so];
            *(uint4*)(vdst + (size_t)hd * SS + so) = val;
        }
    } else {
        bool isq = n0 < 2048;
        unsigned short* dst = isq ? qb : kb;
        float scale = isq ? 0.18033688f : 1.0f;  // q: fold softmax scale * log2(e)
        #pragma unroll
        for (int mi = 0; mi < 4; mi++) {
            int gr = m0 + wm + mi * 16 + lq * 4;
            #pragma unroll
            for (int ni = 0; ni < 4; ni++) {
                int gc = n0 + wn + ni * 16 + lm;
                int rem = gc & 1023;
                int h = rem >> 6, hd = rem & 63;
                #pragma unroll
                for (int r = 0; r < 4; r++) {
                    int row = gr + r;
                    int b = row >> 11, s = row & 2047;
                    dst[(((size_t)b * HH + h) * SS + s) * HDIM + hd] =
                        f2bf(acc[mi][ni][r] * scale);
                }
            }
        }
    }
}

// ---------------------------------------------------------------- Flash attention
// Transposed register-P scheme (S^T = K·Q^T, O^T += V^T·P^T), restructured for
// occupancy: Q-tile 64 (grid 1024 = 4 blocks/CU -> 16 waves/CU), K-tile 128
// (half the barriers). 4 waves x 16 Q-rows.
__global__ __launch_bounds__(256, 4) void attn(
    const unsigned short* __restrict__ qb,  // [B,H,S,HD] pre-scaled (incl. log2e)
    const unsigned short* __restrict__ kb,  // [B,H,S,HD]
    const unsigned short* __restrict__ vb,  // [B,H,HD,S] (transposed)
    unsigned short* __restrict__ ob) {      // [B,S,D]
    int bh = blockIdx.y;
    int q0 = blockIdx.x * 64;
    int tid = threadIdx.x, lane = tid & 63, wave = tid >> 6;
    int lm = lane & 15, lq = lane >> 4;

    // Kt: [kpos 128][hd 64 +8 pad] = 9216 shorts; Vt: [hd 64][kpos 128 +8] = 8704
    __shared__ unsigned short smem[128 * 72 + 64 * 136];  // 35840 shorts = 35.8 KB
    unsigned short* Kt = smem;
    unsigned short* Vt = smem + 128 * 72;

    const unsigned short* qg = qb + (size_t)bh * SS * HDIM;
    const unsigned short* kg = kb + (size_t)bh * SS * HDIM;
    const unsigned short* vg = vb + (size_t)bh * HDIM * SS;

    // Q fragments, B-operand of S^T: n=q=lane&15, k=hd=lq*8+j
    U4S8 qf[2];
    #pragma unroll
    for (int ks = 0; ks < 2; ks++)
        qf[ks].u = *(const uint4*)(
            qg + (size_t)(q0 + wave * 16 + lm) * HDIM + ks * 32 + lq * 8);

    f32x4 oacc[4] = {};   // O^T[hd-tile]: col=q=lm, row=hd=lq*4+r (+16*mi2)
    float lsum = 0.f;     // per-lane partial over this lane's k set

    // staging indices: Kt 128 rows x 64 shorts, 2 thr/row x 32 shorts;
    //                  Vt  64 rows x 128 shorts, 4 thr/row x 32 shorts
    int krow = tid >> 1, kof = (tid & 1) * 32;
    int vrow = tid >> 2, vof = (tid & 3) * 32;

    for (int kt = 0; kt < SS / 128; kt++) {
        uint4 kv[4], vv[4];
        const unsigned short* kp = kg + (size_t)(kt * 128 + krow) * HDIM + kof;
        const unsigned short* vp = vg + (size_t)vrow * SS + kt * 128 + vof;
        #pragma unroll
        for (int i = 0; i < 4; i++) { kv[i] = *(const uint4*)(kp + i * 8); }
        #pragma unroll
        for (int i = 0; i < 4; i++) { vv[i] = *(const uint4*)(vp + i * 8); }
        __syncthreads();  // all waves done reading previous Kt/Vt
        #pragma unroll
        for (int i = 0; i < 4; i++)
            *(uint4*)(Kt + krow * 72 + kof + i * 8) = kv[i];
        #pragma unroll
        for (int i = 0; i < 4; i++)
            *(uint4*)(Vt + vrow * 136 + vof + i * 8) = vv[i];
        __syncthreads();

        // ---- S^T[kpos][q] then P^T = 2^(S^T) in registers (C-layout == PV B-layout)
        U2S4 pb[8];
        #pragma unroll
        for (int mi = 0; mi < 8; mi++) {
            U4S8 kf0, kf1;
            kf0.u = *(const uint4*)(Kt + (mi * 16 + lm) * 72 + lq * 8);
            kf1.u = *(const uint4*)(Kt + (mi * 16 + lm) * 72 + 32 + lq * 8);
            f32x4 sa = {};
            sa = __builtin_amdgcn_mfma_f32_16x16x32_bf16(kf0.s, qf[0].s, sa, 0, 0, 0);
            sa = __builtin_amdgcn_mfma_f32_16x16x32_bf16(kf1.s, qf[1].s, sa, 0, 0, 0);
            #pragma unroll
            for (int r = 0; r < 4; r++) {
                float p = exp2f(sa[r]);
                lsum += p;
                pb[mi].h[r] = f2bf_fast(p);
            }
        }

        // ---- O^T[hd][q] += V^T[hd][k] * P^T[k][q]  (16x16x16, A=V^T b64 frags)
        #pragma unroll
        for (int mi2 = 0; mi2 < 4; mi2++) {
            #pragma unroll
            for (int kc = 0; kc < 8; kc++) {
                U2S4 vf;
                vf.u = *(const uint2*)(Vt + (mi2 * 16 + lm) * 136 + kc * 16 + lq * 4);
                oacc[mi2] = MFMA_PV(vf.s, pb[kc].s, oacc[mi2]);
            }
        }
    }

    // ---- row sum: lanes lm, lm+16, lm+32, lm+48 hold disjoint k partials
    float s = lsum;
    s += __shfl_xor(s, 16);
    s += __shfl_xor(s, 32);
    float inv = 1.f / s;

    // ---- transpose O^T back via freed smem, store coalesced bf16 [B,S,D]
    __syncthreads();  // everyone done with Kt/Vt
    unsigned short* Ow = smem + wave * (16 * 72);
    #pragma unroll
    for (int mi2 = 0; mi2 < 4; mi2++) {
        U2S4 t;
        #pragma unroll
        for (int r = 0; r < 4; r++)
            t.h[r] = f2bf(oacc[mi2][r] * inv);
        *(uint2*)&Ow[lm * 72 + mi2 * 16 + lq * 4] = t.u;
    }
    __builtin_amdgcn_wave_barrier();  // Ow wave-local
    int b = bh >> 4, h = bh & 15;
    #pragma unroll
    for (int it = 0; it < 2; it++) {
        int q  = it * 8 + (lane >> 3);
        int off = (lane & 7) * 8;
        uint4 val = *(const uint4*)&Ow[q * 72 + off];
        int srow = q0 + wave * 16 + q;
        *(uint4*)(ob + (size_t)(b * SS + srow) * DD + h * 64 + off) = val;
    }
}

// ---------------------------------------------------------------- Output GEMM
// out[m,e] = sum_d o[m,d] * w_out[e,d] + b_out[e].  M=4096, N=1024, K=1024.
// 128x64 tile -> 512 blocks (2/CU).
__global__ __launch_bounds__(256) void gemm_out(
    const unsigned short* __restrict__ A,   // o_bf   [4096][1024]
    const unsigned short* __restrict__ Bw,  // wout_bf[1024][1024]
    const float* __restrict__ bias, float* __restrict__ out) {
    const int K = 1024;
    __shared__ unsigned short As[128 * 32];
    __shared__ unsigned short Bs[64 * 32];
    int tid = threadIdx.x;
    int lane = tid & 63, wave = tid >> 6;
    int wm = (wave & 1) * 64, wn = (wave >> 1) * 32;
    int m0 = blockIdx.y * 128, n0 = blockIdx.x * 64;
    int lm = lane & 15, lq = lane >> 4;

    f32x4 acc[4][2] = {};

    int srow = tid >> 2, schunk = tid & 3;
    const unsigned short* gA = A  + (size_t)(m0 + srow) * K + schunk * 8;
    unsigned short* lA = As + srow * 32 + schunk * 8;
    int srB = tid >> 2;
    const unsigned short* gB = Bw + (size_t)(n0 + srB) * K + schunk * 8;
    unsigned short* lB = Bs + srB * 32 + schunk * 8;

    for (int k0 = 0; k0 < K; k0 += 32) {
        async_cp16(gA + k0,           lA);
        async_cp16(gA + 64 * K + k0,  lA + 64 * 32);
        async_cp16(gB + k0,           lB);
        __syncthreads();
        U4S8 af[4], bfx[2];
        #pragma unroll
        for (int i = 0; i < 4; i++)
            af[i].u = *(const uint4*)(As + (wm + i * 16 + lm) * 32 + lq * 8);
        #pragma unroll
        for (int i = 0; i < 2; i++)
            bfx[i].u = *(const uint4*)(Bs + (wn + i * 16 + lm) * 32 + lq * 8);
        #pragma unroll
        for (int mi = 0; mi < 4; mi++)
            #pragma unroll
            for (int ni = 0; ni < 2; ni++)
                acc[mi][ni] = __builtin_amdgcn_mfma_f32_16x16x32_bf16(
                    af[mi].s, bfx[ni].s, acc[mi][ni], 0, 0, 0);
        __syncthreads();
    }

    #pragma unroll
    for (int mi = 0; mi < 4; mi++) {
        int gr = m0 + wm + mi * 16 + lq * 4;
        #pragma unroll
        for (int ni = 0; ni < 2; ni++) {
            int gc = n0 + wn + ni * 16 + lm;
            float bv = bias[gc];
            #pragma unroll
            for (int r = 0; r < 4; r++)
                out[(size_t)(gr + r) * DD + gc] = acc[mi][ni][r] + bv;
        }
    }
}

// ---------------------------------------------------------------- launch
extern "C" void kernel_launch(void* const* d_in, const int* in_sizes, int n_in,
                              void* d_out, int out_size, void* d_ws, size_t ws_size,
                              hipStream_t stream) {
    const float* x     = (const float*)d_in[0];
    const float* w_qkv = (const float*)d_in[1];
    const float* w_out = (const float*)d_in[2];
    const float* b_out = (const float*)d_in[3];
    float* out = (float*)d_out;

    unsigned short* ws = (unsigned short*)d_ws;
    const size_t NX = (size_t)BB * SS * DD;        // 4,194,304
    unsigned short* x_bf    = ws;
    unsigned short* wqkv_bf = x_bf + NX;
    unsigned short* wout_bf = wqkv_bf + 3145728;
    unsigned short* q_buf   = wout_bf + 1048576;
    unsigned short* k_buf   = q_buf + NX;
    unsigned short* v_buf   = k_buf + NX;
    unsigned short* o_buf   = v_buf + NX;

    cvt_all<<<4096, 256, 0, stream>>>(x, w_qkv, w_out, x_bf, wqkv_bf, wout_bf);
    gemm_qkv<<<dim3(24, 32), 256, 0, stream>>>(x_bf, wqkv_bf, q_buf, k_buf, v_buf);
    attn<<<dim3(32, 32), 256, 0, stream>>>(q_buf, k_buf, v_buf, o_buf);
    gemm_out<<<dim3(16, 32), 256, 0, stream>>>(o_buf, wout_bf, b_out, out);
}

// Round 8
// 219.978 us; speedup vs baseline: 1.5324x; 1.5324x over previous
//
#include <hip/hip_runtime.h>
#include <cstdint>
#include <cstddef>

// Problem constants
#define BB 2
#define SS 2048
#define DD 1024
#define HH 16
#define HDIM 64
// Attention scale 1/sqrt(64)=0.125 and the exp->exp2 fold log2(e) are
// pre-multiplied into q at the gemm_qkv epilogue: 0.125*1.4426950 = 0.18033688.

typedef short bf16x8 __attribute__((ext_vector_type(8)));
typedef short bf16x4 __attribute__((ext_vector_type(4)));
typedef float f32x4 __attribute__((ext_vector_type(4)));

union U4S8 { uint4 u; bf16x8 s; };
union U2S4 { uint2 u; bf16x4 s; unsigned short h[4]; };

// 16x16x16 bf16 MFMA (K=16). __has_builtin(amdgcn) is FALSE in the host pass
// of HIP's dual compile — guard with __HIP_DEVICE_COMPILE__, dummy for host.
#if defined(__HIP_DEVICE_COMPILE__)
# if __has_builtin(__builtin_amdgcn_mfma_f32_16x16x16bf16_1k)
#  define MFMA_PV(a, b, c) __builtin_amdgcn_mfma_f32_16x16x16bf16_1k((a), (b), (c), 0, 0, 0)
# else
#  define MFMA_PV(a, b, c) __builtin_amdgcn_mfma_f32_16x16x16_bf16((a), (b), (c), 0, 0, 0)
# endif
#else
# define MFMA_PV(a, b, c) (c)
#endif

__device__ __forceinline__ unsigned short f2bf(float f) {
    union { float f; unsigned int u; } c; c.f = f;
    unsigned int u = c.u;
    unsigned int r = (u + 0x7FFFu + ((u >> 16) & 1u)) >> 16;  // RTNE
    return (unsigned short)r;
}
// cheap round (ties-away): 2 VALU ops. For P in [0,1] error ~2^-10 relative.
__device__ __forceinline__ unsigned short f2bf_fast(float f) {
    union { float f; unsigned int u; } c; c.f = f;
    return (unsigned short)((c.u + 0x8000u) >> 16);
}

// async global->LDS, 16B per lane. LDS dest must be wave-uniform base + lane*16.
__device__ __forceinline__ void async_cp16(const void* g, void* l) {
    __builtin_amdgcn_global_load_lds(
        (const __attribute__((address_space(1))) void*)g,
        (__attribute__((address_space(3))) void*)l, 16, 0, 0);
}

// ---------------------------------------------------------------- fp32 -> bf16
// One kernel for all three inputs (x:524288, w_qkv:393216, w_out:131072 uint4s).
__global__ __launch_bounds__(256) void cvt_all(
    const float* __restrict__ x, const float* __restrict__ wq,
    const float* __restrict__ wo,
    unsigned short* __restrict__ xb, unsigned short* __restrict__ wqb,
    unsigned short* __restrict__ wob) {
    int i = blockIdx.x * 256 + threadIdx.x;
    const float* in; unsigned short* out; int j;
    if (i < 524288)       { in = x;  out = xb;  j = i; }
    else if (i < 917504)  { in = wq; out = wqb; j = i - 524288; }
    else                  { in = wo; out = wob; j = i - 917504; }
    float4 a = ((const float4*)in)[2 * j];
    float4 b = ((const float4*)in)[2 * j + 1];
    union { uint4 u; unsigned short h[8]; } o;
    o.h[0] = f2bf(a.x); o.h[1] = f2bf(a.y); o.h[2] = f2bf(a.z); o.h[3] = f2bf(a.w);
    o.h[4] = f2bf(b.x); o.h[5] = f2bf(b.y); o.h[6] = f2bf(b.z); o.h[7] = f2bf(b.w);
    ((uint4*)out)[j] = o.u;
}

// ---------------------------------------------------------------- QKV GEMM
// C[m,e] = sum_d x[m,d] * w_qkv[e,d]  (NT). M=4096, N=3072, K=1024.
// 128x128 tile, BK=32, global_load_lds width-16 staging.
// v epilogue transposes through LDS -> coalesced [B,H,HD,S] uint4 stores.
__global__ __launch_bounds__(256) void gemm_qkv(
    const unsigned short* __restrict__ A,   // x_bf   [4096][1024]
    const unsigned short* __restrict__ Bw,  // wqkv_bf[3072][1024]
    unsigned short* __restrict__ qb, unsigned short* __restrict__ kb,
    unsigned short* __restrict__ vb) {
    const int K = 1024;
    __shared__ unsigned short As[128 * 32];
    __shared__ unsigned short Bs[128 * 32];
    __shared__ unsigned short Tr[4][64 * 72];  // per-wave transpose buffer (v epilogue)
    int tid = threadIdx.x;
    int lane = tid & 63, wave = tid >> 6;
    int wm = (wave & 1) * 64, wn = (wave >> 1) * 64;
    int m0 = blockIdx.y * 128, n0 = blockIdx.x * 128;
    int lm = lane & 15, lq = lane >> 4;

    f32x4 acc[4][4] = {};

    int srow = tid >> 2, schunk = tid & 3;
    const unsigned short* gA = A  + (size_t)(m0 + srow) * K + schunk * 8;
    const unsigned short* gB = Bw + (size_t)(n0 + srow) * K + schunk * 8;
    unsigned short* lA = As + srow * 32 + schunk * 8;
    unsigned short* lB = Bs + srow * 32 + schunk * 8;

    for (int k0 = 0; k0 < K; k0 += 32) {
        async_cp16(gA + k0,           lA);
        async_cp16(gA + 64 * K + k0,  lA + 64 * 32);
        async_cp16(gB + k0,           lB);
        async_cp16(gB + 64 * K + k0,  lB + 64 * 32);
        __syncthreads();
        U4S8 af[4], bfx[4];
        #pragma unroll
        for (int i = 0; i < 4; i++) {
            af[i].u  = *(const uint4*)(As + (wm + i * 16 + lm) * 32 + lq * 8);
            bfx[i].u = *(const uint4*)(Bs + (wn + i * 16 + lm) * 32 + lq * 8);
        }
        #pragma unroll
        for (int mi = 0; mi < 4; mi++)
            #pragma unroll
            for (int ni = 0; ni < 4; ni++)
                acc[mi][ni] = __builtin_amdgcn_mfma_f32_16x16x32_bf16(
                    af[mi].s, bfx[ni].s, acc[mi][ni], 0, 0, 0);
        __syncthreads();
    }

    // Epilogue. C/D layout: col=lane&15, row=(lane>>4)*4+reg.
    if (n0 < 1024) {
        // ---- v: transpose wave's 64x64 subtile via LDS, store [B,H,HD,S] coalesced
        int h = (n0 + wn) >> 6;
        #pragma unroll
        for (int mi = 0; mi < 4; mi++)
            #pragma unroll
            for (int ni = 0; ni < 4; ni++)
                #pragma unroll
                for (int r = 0; r < 4; r++)
                    Tr[wave][(ni * 16 + lm) * 72 + mi * 16 + lq * 4 + r] =
                        f2bf(acc[mi][ni][r]);
        __builtin_amdgcn_wave_barrier();
        int b = m0 >> 11;
        int s_base = (m0 + wm) & 2047;
        unsigned short* vdst = vb + ((size_t)(b * HH + h) * HDIM) * SS + s_base;
        #pragma unroll
        for (int it = 0; it < 8; it++) {
            int hd = it * 8 + (lane >> 3);
            int so = (lane & 7) * 8;
            uint4 val = *(const uint4*)&Tr[wave][hd * 72 + so];
            *(uint4*)(vdst + (size_t)hd * SS + so) = val;
        }
    } else {
        bool isq = n0 < 2048;
        unsigned short* dst = isq ? qb : kb;
        float scale = isq ? 0.18033688f : 1.0f;  // q: fold softmax scale * log2(e)
        #pragma unroll
        for (int mi = 0; mi < 4; mi++) {
            int gr = m0 + wm + mi * 16 + lq * 4;
            #pragma unroll
            for (int ni = 0; ni < 4; ni++) {
                int gc = n0 + wn + ni * 16 + lm;
                int rem = gc & 1023;
                int h = rem >> 6, hd = rem & 63;
                #pragma unroll
                for (int r = 0; r < 4; r++) {
                    int row = gr + r;
                    int b = row >> 11, s = row & 2047;
                    dst[(((size_t)b * HH + h) * SS + s) * HDIM + hd] =
                        f2bf(acc[mi][ni][r] * scale);
                }
            }
        }
    }
}

// ---------------------------------------------------------------- Flash attention
// Transposed register-P scheme (S^T = K·Q^T, O^T += V^T·P^T).
// Q-tile 64 (grid 1024 = 4 blocks/CU), K-tile 64 (round-6 staging: 64 B/thread,
// no spill). 4 waves x 16 Q-rows. No launch-bounds minimum — round 7 showed a
// VGPR cap + fat staging = scratch-spill disaster (531 MB scratch writes).
__global__ __launch_bounds__(256) void attn(
    const unsigned short* __restrict__ qb,  // [B,H,S,HD] pre-scaled (incl. log2e)
    const unsigned short* __restrict__ kb,  // [B,H,S,HD]
    const unsigned short* __restrict__ vb,  // [B,H,HD,S] (transposed)
    unsigned short* __restrict__ ob) {      // [B,S,D]
    int bh = blockIdx.y;
    int q0 = blockIdx.x * 64;
    int tid = threadIdx.x, lane = tid & 63, wave = tid >> 6;
    int lm = lane & 15, lq = lane >> 4;

    __shared__ unsigned short smem[2 * 64 * 72];  // Kt | Vt; reused for O epilogue
    unsigned short* Kt = smem;             // [k-pos][hd], pad 72
    unsigned short* Vt = smem + 64 * 72;   // [hd][k-pos], pad 72

    const unsigned short* qg = qb + (size_t)bh * SS * HDIM;
    const unsigned short* kg = kb + (size_t)bh * SS * HDIM;
    const unsigned short* vg = vb + (size_t)bh * HDIM * SS;

    // Q fragments, B-operand of S^T: n=q=lane&15, k=hd=lq*8+j
    U4S8 qf[2];
    #pragma unroll
    for (int ks = 0; ks < 2; ks++)
        qf[ks].u = *(const uint4*)(
            qg + (size_t)(q0 + wave * 16 + lm) * HDIM + ks * 32 + lq * 8);

    f32x4 oacc[4] = {};   // O^T[hd-tile]: col=q=lm, row=hd=lq*4+r (+16*mi2)
    float lsum = 0.f;     // per-lane partial over this lane's k subset

    int krow = tid >> 2, koff = (tid & 3) * 16;

    for (int kt = 0; kt < SS / 64; kt++) {
        uint4 k0v = *(const uint4*)(kg + (size_t)(kt * 64 + krow) * HDIM + koff);
        uint4 k1v = *(const uint4*)(kg + (size_t)(kt * 64 + krow) * HDIM + koff + 8);
        uint4 v0v = *(const uint4*)(vg + (size_t)krow * SS + kt * 64 + koff);
        uint4 v1v = *(const uint4*)(vg + (size_t)krow * SS + kt * 64 + koff + 8);
        __syncthreads();  // all waves done reading previous Kt/Vt
        *(uint4*)(Kt + krow * 72 + koff)     = k0v;
        *(uint4*)(Kt + krow * 72 + koff + 8) = k1v;
        *(uint4*)(Vt + krow * 72 + koff)     = v0v;
        *(uint4*)(Vt + krow * 72 + koff + 8) = v1v;
        __syncthreads();

        // ---- S^T[kpos][q] then P^T = 2^(S^T) in registers (C-layout == PV B-layout)
        U2S4 pb[4];
        #pragma unroll
        for (int mi = 0; mi < 4; mi++) {
            U4S8 kf0, kf1;
            kf0.u = *(const uint4*)(Kt + (mi * 16 + lm) * 72 + lq * 8);
            kf1.u = *(const uint4*)(Kt + (mi * 16 + lm) * 72 + 32 + lq * 8);
            f32x4 sa = {};
            sa = __builtin_amdgcn_mfma_f32_16x16x32_bf16(kf0.s, qf[0].s, sa, 0, 0, 0);
            sa = __builtin_amdgcn_mfma_f32_16x16x32_bf16(kf1.s, qf[1].s, sa, 0, 0, 0);
            #pragma unroll
            for (int r = 0; r < 4; r++) {
                float p = exp2f(sa[r]);
                lsum += p;
                pb[mi].h[r] = f2bf_fast(p);
            }
        }

        // ---- O^T[hd][q] += V^T[hd][k] * P^T[k][q]  (16x16x16, A=V^T b64 frags)
        #pragma unroll
        for (int mi2 = 0; mi2 < 4; mi2++) {
            #pragma unroll
            for (int kc = 0; kc < 4; kc++) {
                U2S4 vf;
                vf.u = *(const uint2*)(Vt + (mi2 * 16 + lm) * 72 + kc * 16 + lq * 4);
                oacc[mi2] = MFMA_PV(vf.s, pb[kc].s, oacc[mi2]);
            }
        }
    }

    // ---- row sum: lanes lm, lm+16, lm+32, lm+48 hold disjoint k partials
    float s = lsum;
    s += __shfl_xor(s, 16);
    s += __shfl_xor(s, 32);
    float inv = 1.f / s;

    // ---- transpose O^T back via freed smem, store coalesced bf16 [B,S,D]
    __syncthreads();  // everyone done with Kt/Vt
    unsigned short* Ow = smem + wave * (16 * 72);
    #pragma unroll
    for (int mi2 = 0; mi2 < 4; mi2++) {
        U2S4 t;
        #pragma unroll
        for (int r = 0; r < 4; r++)
            t.h[r] = f2bf(oacc[mi2][r] * inv);
        *(uint2*)&Ow[lm * 72 + mi2 * 16 + lq * 4] = t.u;
    }
    __builtin_amdgcn_wave_barrier();  // Ow wave-local
    int b = bh >> 4, h = bh & 15;
    #pragma unroll
    for (int it = 0; it < 2; it++) {
        int q  = it * 8 + (lane >> 3);
        int off = (lane & 7) * 8;
        uint4 val = *(const uint4*)&Ow[q * 72 + off];
        int srow = q0 + wave * 16 + q;
        *(uint4*)(ob + (size_t)(b * SS + srow) * DD + h * 64 + off) = val;
    }
}

// ---------------------------------------------------------------- Output GEMM
// out[m,e] = sum_d o[m,d] * w_out[e,d] + b_out[e].  M=4096, N=1024, K=1024.
// 128x64 tile -> 512 blocks (2/CU).
__global__ __launch_bounds__(256) void gemm_out(
    const unsigned short* __restrict__ A,   // o_bf   [4096][1024]
    const unsigned short* __restrict__ Bw,  // wout_bf[1024][1024]
    const float* __restrict__ bias, float* __restrict__ out) {
    const int K = 1024;
    __shared__ unsigned short As[128 * 32];
    __shared__ unsigned short Bs[64 * 32];
    int tid = threadIdx.x;
    int lane = tid & 63, wave = tid >> 6;
    int wm = (wave & 1) * 64, wn = (wave >> 1) * 32;
    int m0 = blockIdx.y * 128, n0 = blockIdx.x * 64;
    int lm = lane & 15, lq = lane >> 4;

    f32x4 acc[4][2] = {};

    int srow = tid >> 2, schunk = tid & 3;
    const unsigned short* gA = A  + (size_t)(m0 + srow) * K + schunk * 8;
    unsigned short* lA = As + srow * 32 + schunk * 8;
    int srB = tid >> 2;
    const unsigned short* gB = Bw + (size_t)(n0 + srB) * K + schunk * 8;
    unsigned short* lB = Bs + srB * 32 + schunk * 8;

    for (int k0 = 0; k0 < K; k0 += 32) {
        async_cp16(gA + k0,           lA);
        async_cp16(gA + 64 * K + k0,  lA + 64 * 32);
        async_cp16(gB + k0,           lB);
        __syncthreads();
        U4S8 af[4], bfx[2];
        #pragma unroll
        for (int i = 0; i < 4; i++)
            af[i].u = *(const uint4*)(As + (wm + i * 16 + lm) * 32 + lq * 8);
        #pragma unroll
        for (int i = 0; i < 2; i++)
            bfx[i].u = *(const uint4*)(Bs + (wn + i * 16 + lm) * 32 + lq * 8);
        #pragma unroll
        for (int mi = 0; mi < 4; mi++)
            #pragma unroll
            for (int ni = 0; ni < 2; ni++)
                acc[mi][ni] = __builtin_amdgcn_mfma_f32_16x16x32_bf16(
                    af[mi].s, bfx[ni].s, acc[mi][ni], 0, 0, 0);
        __syncthreads();
    }

    #pragma unroll
    for (int mi = 0; mi < 4; mi++) {
        int gr = m0 + wm + mi * 16 + lq * 4;
        #pragma unroll
        for (int ni = 0; ni < 2; ni++) {
            int gc = n0 + wn + ni * 16 + lm;
            float bv = bias[gc];
            #pragma unroll
            for (int r = 0; r < 4; r++)
                out[(size_t)(gr + r) * DD + gc] = acc[mi][ni][r] + bv;
        }
    }
}

// ---------------------------------------------------------------- launch
extern "C" void kernel_launch(void* const* d_in, const int* in_sizes, int n_in,
                              void* d_out, int out_size, void* d_ws, size_t ws_size,
                              hipStream_t stream) {
    const float* x     = (const float*)d_in[0];
    const float* w_qkv = (const float*)d_in[1];
    const float* w_out = (const float*)d_in[2];
    const float* b_out = (const float*)d_in[3];
    float* out = (float*)d_out;

    unsigned short* ws = (unsigned short*)d_ws;
    const size_t NX = (size_t)BB * SS * DD;        // 4,194,304
    unsigned short* x_bf    = ws;
    unsigned short* wqkv_bf = x_bf + NX;
    unsigned short* wout_bf = wqkv_bf + 3145728;
    unsigned short* q_buf   = wout_bf + 1048576;
    unsigned short* k_buf   = q_buf + NX;
    unsigned short* v_buf   = k_buf + NX;
    unsigned short* o_buf   = v_buf + NX;

    cvt_all<<<4096, 256, 0, stream>>>(x, w_qkv, w_out, x_bf, wqkv_bf, wout_bf);
    gemm_qkv<<<dim3(24, 32), 256, 0, stream>>>(x_bf, wqkv_bf, q_buf, k_buf, v_buf);
    attn<<<dim3(32, 32), 256, 0, stream>>>(q_buf, k_buf, v_buf, o_buf);
    gemm_out<<<dim3(16, 32), 256, 0, stream>>>(o_buf, wout_bf, b_out, out);
}

// Round 9
// 212.379 us; speedup vs baseline: 1.5873x; 1.0358x over previous
//
#include <hip/hip_runtime.h>
#include <cstdint>
#include <cstddef>

// Problem constants
#define BB 2
#define SS 2048
#define DD 1024
#define HH 16
#define HDIM 64
// Attention scale 1/sqrt(64)=0.125 and the exp->exp2 fold log2(e) are
// pre-multiplied into q at the gemm_qkv epilogue: 0.125*1.4426950 = 0.18033688.

typedef short bf16x8 __attribute__((ext_vector_type(8)));
typedef short bf16x4 __attribute__((ext_vector_type(4)));
typedef float f32x4 __attribute__((ext_vector_type(4)));

union U4S8 { uint4 u; bf16x8 s; };
union U2S4 { uint2 u; bf16x4 s; unsigned short h[4]; };

// 16x16x16 bf16 MFMA (K=16). __has_builtin(amdgcn) is FALSE in the host pass
// of HIP's dual compile — guard with __HIP_DEVICE_COMPILE__, dummy for host.
#if defined(__HIP_DEVICE_COMPILE__)
# if __has_builtin(__builtin_amdgcn_mfma_f32_16x16x16bf16_1k)
#  define MFMA_PV(a, b, c) __builtin_amdgcn_mfma_f32_16x16x16bf16_1k((a), (b), (c), 0, 0, 0)
# else
#  define MFMA_PV(a, b, c) __builtin_amdgcn_mfma_f32_16x16x16_bf16((a), (b), (c), 0, 0, 0)
# endif
#else
# define MFMA_PV(a, b, c) (c)
#endif

__device__ __forceinline__ unsigned short f2bf(float f) {
    union { float f; unsigned int u; } c; c.f = f;
    unsigned int u = c.u;
    unsigned int r = (u + 0x7FFFu + ((u >> 16) & 1u)) >> 16;  // RTNE
    return (unsigned short)r;
}
// cheap round (ties-away): 2 VALU ops. For P in [0,1] error ~2^-10 relative.
__device__ __forceinline__ unsigned short f2bf_fast(float f) {
    union { float f; unsigned int u; } c; c.f = f;
    return (unsigned short)((c.u + 0x8000u) >> 16);
}

// async global->LDS, 16B per lane. LDS dest must be wave-uniform base + lane*16.
__device__ __forceinline__ void async_cp16(const void* g, void* l) {
    __builtin_amdgcn_global_load_lds(
        (const __attribute__((address_space(1))) void*)g,
        (__attribute__((address_space(3))) void*)l, 16, 0, 0);
}

// ---------------------------------------------------------------- fp32 -> bf16
// One kernel for all three inputs (x:524288, w_qkv:393216, w_out:131072 uint4s).
__global__ __launch_bounds__(256) void cvt_all(
    const float* __restrict__ x, const float* __restrict__ wq,
    const float* __restrict__ wo,
    unsigned short* __restrict__ xb, unsigned short* __restrict__ wqb,
    unsigned short* __restrict__ wob) {
    int i = blockIdx.x * 256 + threadIdx.x;
    const float* in; unsigned short* out; int j;
    if (i < 524288)       { in = x;  out = xb;  j = i; }
    else if (i < 917504)  { in = wq; out = wqb; j = i - 524288; }
    else                  { in = wo; out = wob; j = i - 917504; }
    float4 a = ((const float4*)in)[2 * j];
    float4 b = ((const float4*)in)[2 * j + 1];
    union { uint4 u; unsigned short h[8]; } o;
    o.h[0] = f2bf(a.x); o.h[1] = f2bf(a.y); o.h[2] = f2bf(a.z); o.h[3] = f2bf(a.w);
    o.h[4] = f2bf(b.x); o.h[5] = f2bf(b.y); o.h[6] = f2bf(b.z); o.h[7] = f2bf(b.w);
    ((uint4*)out)[j] = o.u;
}

// ---------------------------------------------------------------- QKV GEMM
// C[m,e] = sum_d x[m,d] * w_qkv[e,d]  (NT). M=4096, N=3072, K=1024.
// 128x128 tile, BK=32, global_load_lds width-16 staging.
// v epilogue transposes through LDS -> coalesced [B,H,HD,S] uint4 stores.
__global__ __launch_bounds__(256) void gemm_qkv(
    const unsigned short* __restrict__ A,   // x_bf   [4096][1024]
    const unsigned short* __restrict__ Bw,  // wqkv_bf[3072][1024]
    unsigned short* __restrict__ qb, unsigned short* __restrict__ kb,
    unsigned short* __restrict__ vb) {
    const int K = 1024;
    __shared__ unsigned short As[128 * 32];
    __shared__ unsigned short Bs[128 * 32];
    __shared__ unsigned short Tr[4][64 * 72];  // per-wave transpose buffer (v epilogue)
    int tid = threadIdx.x;
    int lane = tid & 63, wave = tid >> 6;
    int wm = (wave & 1) * 64, wn = (wave >> 1) * 64;
    int m0 = blockIdx.y * 128, n0 = blockIdx.x * 128;
    int lm = lane & 15, lq = lane >> 4;

    f32x4 acc[4][4] = {};

    int srow = tid >> 2, schunk = tid & 3;
    const unsigned short* gA = A  + (size_t)(m0 + srow) * K + schunk * 8;
    const unsigned short* gB = Bw + (size_t)(n0 + srow) * K + schunk * 8;
    unsigned short* lA = As + srow * 32 + schunk * 8;
    unsigned short* lB = Bs + srow * 32 + schunk * 8;

    for (int k0 = 0; k0 < K; k0 += 32) {
        async_cp16(gA + k0,           lA);
        async_cp16(gA + 64 * K + k0,  lA + 64 * 32);
        async_cp16(gB + k0,           lB);
        async_cp16(gB + 64 * K + k0,  lB + 64 * 32);
        __syncthreads();
        U4S8 af[4], bfx[4];
        #pragma unroll
        for (int i = 0; i < 4; i++) {
            af[i].u  = *(const uint4*)(As + (wm + i * 16 + lm) * 32 + lq * 8);
            bfx[i].u = *(const uint4*)(Bs + (wn + i * 16 + lm) * 32 + lq * 8);
        }
        #pragma unroll
        for (int mi = 0; mi < 4; mi++)
            #pragma unroll
            for (int ni = 0; ni < 4; ni++)
                acc[mi][ni] = __builtin_amdgcn_mfma_f32_16x16x32_bf16(
                    af[mi].s, bfx[ni].s, acc[mi][ni], 0, 0, 0);
        __syncthreads();
    }

    // Epilogue. C/D layout: col=lane&15, row=(lane>>4)*4+reg.
    if (n0 < 1024) {
        // ---- v: transpose wave's 64x64 subtile via LDS, store [B,H,HD,S] coalesced
        int h = (n0 + wn) >> 6;
        #pragma unroll
        for (int mi = 0; mi < 4; mi++)
            #pragma unroll
            for (int ni = 0; ni < 4; ni++)
                #pragma unroll
                for (int r = 0; r < 4; r++)
                    Tr[wave][(ni * 16 + lm) * 72 + mi * 16 + lq * 4 + r] =
                        f2bf(acc[mi][ni][r]);
        __builtin_amdgcn_wave_barrier();
        int b = m0 >> 11;
        int s_base = (m0 + wm) & 2047;
        unsigned short* vdst = vb + ((size_t)(b * HH + h) * HDIM) * SS + s_base;
        #pragma unroll
        for (int it = 0; it < 8; it++) {
            int hd = it * 8 + (lane >> 3);
            int so = (lane & 7) * 8;
            uint4 val = *(const uint4*)&Tr[wave][hd * 72 + so];
            *(uint4*)(vdst + (size_t)hd * SS + so) = val;
        }
    } else {
        bool isq = n0 < 2048;
        unsigned short* dst = isq ? qb : kb;
        float scale = isq ? 0.18033688f : 1.0f;  // q: fold softmax scale * log2(e)
        #pragma unroll
        for (int mi = 0; mi < 4; mi++) {
            int gr = m0 + wm + mi * 16 + lq * 4;
            #pragma unroll
            for (int ni = 0; ni < 4; ni++) {
                int gc = n0 + wn + ni * 16 + lm;
                int rem = gc & 1023;
                int h = rem >> 6, hd = rem & 63;
                #pragma unroll
                for (int r = 0; r < 4; r++) {
                    int row = gr + r;
                    int b = row >> 11, s = row & 2047;
                    dst[(((size_t)b * HH + h) * SS + s) * HDIM + hd] =
                        f2bf(acc[mi][ni][r] * scale);
                }
            }
        }
    }
}

// ---------------------------------------------------------------- Flash attention
// Transposed register-P scheme (S^T = K·Q^T, O^T += V^T·P^T), now with:
//  * async global_load_lds staging into DOUBLE-buffered LDS (one barrier/tile;
//    loads for tile kt+1 fly during tile kt's compute, drained by next barrier)
//  * XOR-swizzled unpadded LDS (chunk' = chunk ^ (row&7)): conflict-free b128/b64
//    reads AND lane-contiguous async writes; all read addrs loop-invariant VGPRs.
// Q-tile 64 (grid 1024 = 4 blocks/CU), K-tile 64, 4 waves x 16 Q-rows.
__global__ __launch_bounds__(256) void attn(
    const unsigned short* __restrict__ qb,  // [B,H,S,HD] pre-scaled (incl. log2e)
    const unsigned short* __restrict__ kb,  // [B,H,S,HD]
    const unsigned short* __restrict__ vb,  // [B,H,HD,S] (transposed)
    unsigned short* __restrict__ ob) {      // [B,S,D]
    int bh = blockIdx.y;
    int q0 = blockIdx.x * 64;
    int tid = threadIdx.x, lane = tid & 63, wave = tid >> 6;
    int lm = lane & 15, lq = lane >> 4;

    // Double buffer: [bufA: Kt 64x64 | Vt 64x64][bufB: same] = 32 KB, no padding.
    __shared__ unsigned short smem[4 * 4096];

    const unsigned short* qg = qb + (size_t)bh * SS * HDIM;
    const unsigned short* kg = kb + (size_t)bh * SS * HDIM;
    const unsigned short* vg = vb + (size_t)bh * HDIM * SS;

    // Q fragments, B-operand of S^T: n=q=lane&15, k=hd=lq*8+j
    U4S8 qf[2];
    #pragma unroll
    for (int ks = 0; ks < 2; ks++)
        qf[ks].u = *(const uint4*)(
            qg + (size_t)(q0 + wave * 16 + lm) * HDIM + ks * 32 + lq * 8);

    f32x4 oacc[4] = {};   // O^T[hd-tile]: col=q=lm, row=hd=lq*4+r (+16*mi2)
    float lsum = 0.f;     // per-lane partial over this lane's k subset

    // ---- loop-invariant swizzled LDS read indices (shorts)
    int lm7 = lm & 7;
    int kidx = lm * 64 + 8 * (lq ^ lm7);          // kf chunk lq (hd 0..31)
    // kf chunk lq+4 (hd 32..63) = kidx ^ 32
    int vidx[4];
    #pragma unroll
    for (int kc = 0; kc < 4; kc++)
        vidx[kc] = lm * 64 + 8 * (((kc << 1) | (lq >> 1)) ^ lm7) + (lq & 1) * 4;

    // ---- staging indices (async: dest = wave-uniform base + lane*16B)
    int srow = tid >> 3;                  // 0..31
    int scl  = (tid & 7) ^ (srow & 7);    // logical chunk for physical chunk tid&7
    int sdst = tid * 8;                   // shorts
    const unsigned short* ksrc0 = kg + (size_t)srow * HDIM + scl * 8;
    const unsigned short* vsrc0 = vg + (size_t)srow * SS + scl * 8;

    // stage tile kt into buf (Kt at buf, Vt at buf+4096)
    #define STAGE(ktile, buf)                                                   \
        do {                                                                    \
            int _o = (ktile) * 64;                                              \
            async_cp16(ksrc0 + (size_t)_o * HDIM,                smem + (buf) + sdst);         \
            async_cp16(ksrc0 + (size_t)(_o + 32) * HDIM,         smem + (buf) + 2048 + sdst);  \
            async_cp16(vsrc0 + _o,                               smem + (buf) + 4096 + sdst);  \
            async_cp16(vsrc0 + (size_t)32 * SS + _o,             smem + (buf) + 6144 + sdst);  \
        } while (0)

    STAGE(0, 0);

    for (int kt = 0; kt < SS / 64; kt += 2) {
        #pragma unroll
        for (int half = 0; half < 2; half++) {
            int base = half ? 8192 : 0;       // compute buffer
            int obuf = half ? 0 : 8192;       // stage target (other buffer)
            __syncthreads();  // drains vmcnt: this buffer's loads landed; all
                              // waves done computing from the other buffer
            STAGE((kt + 1 + half) & 31, obuf);  // wraps harmlessly on last iter

            // ---- S^T[kpos][q] then P^T = 2^(S^T) in regs (C-layout == PV B-layout)
            U2S4 pb[4];
            #pragma unroll
            for (int mi = 0; mi < 4; mi++) {
                U4S8 kf0, kf1;
                kf0.u = *(const uint4*)(smem + base + mi * 1024 + kidx);
                kf1.u = *(const uint4*)(smem + base + mi * 1024 + (kidx ^ 32));
                f32x4 sa = {};
                sa = __builtin_amdgcn_mfma_f32_16x16x32_bf16(kf0.s, qf[0].s, sa, 0, 0, 0);
                sa = __builtin_amdgcn_mfma_f32_16x16x32_bf16(kf1.s, qf[1].s, sa, 0, 0, 0);
                #pragma unroll
                for (int r = 0; r < 4; r++) {
                    float p = exp2f(sa[r]);
                    lsum += p;
                    pb[mi].h[r] = f2bf_fast(p);
                }
            }

            // ---- O^T[hd][q] += V^T[hd][k] * P^T[k][q]  (16x16x16)
            #pragma unroll
            for (int mi2 = 0; mi2 < 4; mi2++) {
                #pragma unroll
                for (int kc = 0; kc < 4; kc++) {
                    U2S4 vf;
                    vf.u = *(const uint2*)(smem + base + 4096 + mi2 * 1024 + vidx[kc]);
                    oacc[mi2] = MFMA_PV(vf.s, pb[kc].s, oacc[mi2]);
                }
            }
        }
    }
    #undef STAGE

    // ---- row sum: lanes lm, lm+16, lm+32, lm+48 hold disjoint k partials
    float s = lsum;
    s += __shfl_xor(s, 16);
    s += __shfl_xor(s, 32);
    float inv = 1.f / s;

    // ---- transpose O^T back via smem, store coalesced bf16 [B,S,D]
    __syncthreads();  // all compute done; also drains the wrapped stray loads
    unsigned short* Ow = smem + wave * (16 * 72);
    #pragma unroll
    for (int mi2 = 0; mi2 < 4; mi2++) {
        U2S4 t;
        #pragma unroll
        for (int r = 0; r < 4; r++)
            t.h[r] = f2bf(oacc[mi2][r] * inv);
        *(uint2*)&Ow[lm * 72 + mi2 * 16 + lq * 4] = t.u;
    }
    __builtin_amdgcn_wave_barrier();  // Ow wave-local
    int b = bh >> 4, h = bh & 15;
    #pragma unroll
    for (int it = 0; it < 2; it++) {
        int q  = it * 8 + (lane >> 3);
        int off = (lane & 7) * 8;
        uint4 val = *(const uint4*)&Ow[q * 72 + off];
        int srw = q0 + wave * 16 + q;
        *(uint4*)(ob + (size_t)(b * SS + srw) * DD + h * 64 + off) = val;
    }
}

// ---------------------------------------------------------------- Output GEMM
// out[m,e] = sum_d o[m,d] * w_out[e,d] + b_out[e].  M=4096, N=1024, K=1024.
// 128x64 tile -> 512 blocks (2/CU).
__global__ __launch_bounds__(256) void gemm_out(
    const unsigned short* __restrict__ A,   // o_bf   [4096][1024]
    const unsigned short* __restrict__ Bw,  // wout_bf[1024][1024]
    const float* __restrict__ bias, float* __restrict__ out) {
    const int K = 1024;
    __shared__ unsigned short As[128 * 32];
    __shared__ unsigned short Bs[64 * 32];
    int tid = threadIdx.x;
    int lane = tid & 63, wave = tid >> 6;
    int wm = (wave & 1) * 64, wn = (wave >> 1) * 32;
    int m0 = blockIdx.y * 128, n0 = blockIdx.x * 64;
    int lm = lane & 15, lq = lane >> 4;

    f32x4 acc[4][2] = {};

    int srow = tid >> 2, schunk = tid & 3;
    const unsigned short* gA = A  + (size_t)(m0 + srow) * K + schunk * 8;
    unsigned short* lA = As + srow * 32 + schunk * 8;
    int srB = tid >> 2;
    const unsigned short* gB = Bw + (size_t)(n0 + srB) * K + schunk * 8;
    unsigned short* lB = Bs + srB * 32 + schunk * 8;

    for (int k0 = 0; k0 < K; k0 += 32) {
        async_cp16(gA + k0,           lA);
        async_cp16(gA + 64 * K + k0,  lA + 64 * 32);
        async_cp16(gB + k0,           lB);
        __syncthreads();
        U4S8 af[4], bfx[2];
        #pragma unroll
        for (int i = 0; i < 4; i++)
            af[i].u = *(const uint4*)(As + (wm + i * 16 + lm) * 32 + lq * 8);
        #pragma unroll
        for (int i = 0; i < 2; i++)
            bfx[i].u = *(const uint4*)(Bs + (wn + i * 16 + lm) * 32 + lq * 8);
        #pragma unroll
        for (int mi = 0; mi < 4; mi++)
            #pragma unroll
            for (int ni = 0; ni < 2; ni++)
                acc[mi][ni] = __builtin_amdgcn_mfma_f32_16x16x32_bf16(
                    af[mi].s, bfx[ni].s, acc[mi][ni], 0, 0, 0);
        __syncthreads();
    }

    #pragma unroll
    for (int mi = 0; mi < 4; mi++) {
        int gr = m0 + wm + mi * 16 + lq * 4;
        #pragma unroll
        for (int ni = 0; ni < 2; ni++) {
            int gc = n0 + wn + ni * 16 + lm;
            float bv = bias[gc];
            #pragma unroll
            for (int r = 0; r < 4; r++)
                out[(size_t)(gr + r) * DD + gc] = acc[mi][ni][r] + bv;
        }
    }
}

// ---------------------------------------------------------------- launch
extern "C" void kernel_launch(void* const* d_in, const int* in_sizes, int n_in,
                              void* d_out, int out_size, void* d_ws, size_t ws_size,
                              hipStream_t stream) {
    const float* x     = (const float*)d_in[0];
    const float* w_qkv = (const float*)d_in[1];
    const float* w_out = (const float*)d_in[2];
    const float* b_out = (const float*)d_in[3];
    float* out = (float*)d_out;

    unsigned short* ws = (unsigned short*)d_ws;
    const size_t NX = (size_t)BB * SS * DD;        // 4,194,304
    unsigned short* x_bf    = ws;
    unsigned short* wqkv_bf = x_bf + NX;
    unsigned short* wout_bf = wqkv_bf + 3145728;
    unsigned short* q_buf   = wout_bf + 1048576;
    unsigned short* k_buf   = q_buf + NX;
    unsigned short* v_buf   = k_buf + NX;
    unsigned short* o_buf   = v_buf + NX;

    cvt_all<<<4096, 256, 0, stream>>>(x, w_qkv, w_out, x_bf, wqkv_bf, wout_bf);
    gemm_qkv<<<dim3(24, 32), 256, 0, stream>>>(x_bf, wqkv_bf, q_buf, k_buf, v_buf);
    attn<<<dim3(32, 32), 256, 0, stream>>>(q_buf, k_buf, v_buf, o_buf);
    gemm_out<<<dim3(16, 32), 256, 0, stream>>>(o_buf, wout_bf, b_out, out);
}